// Round 1
// baseline (74.704 us; speedup 1.0000x reference)
//
#include <hip/hip_runtime.h>
#include <math.h>

#define TAU 1e-6f

constexpr int Mm = 8;       // sources
constexpr int Bb = 8;       // batch
constexpr int Tt = 32000;   // time
constexpr int NPAIR = 36;   // upper triangle incl diag of 8x8
constexpr int NSTAT = 2 + 16 + NPAIR;   // 54 stats per b
constexpr int WS_STRIDE = 64;           // padded per-b stride in floats

// Kernel 1: per-b reductions over T.
// ws layout per b (stride WS_STRIDE floats):
//   [0..1]   E[j]        = sum_t x_j^2
//   [2..17]  C[j][m]     = sum_t x_j * s_m      (index 2 + j*8 + m)
//   [18..53] G[m<=m']    = sum_t s_m * s_m'     (upper triangle, row-major)
__global__ void mixit_reduce_kernel(const float* __restrict__ es,
                                    const float* __restrict__ im,
                                    float* __restrict__ ws) {
    const int b   = blockIdx.y;
    const int tid = threadIdx.x;

    float acc[NSTAT];
#pragma unroll
    for (int i = 0; i < NSTAT; ++i) acc[i] = 0.0f;

    const float* esb = es + (size_t)b * Mm * Tt;
    const float* imb = im + (size_t)b * 2 * Tt;

    for (int t = blockIdx.x * blockDim.x + tid; t < Tt; t += gridDim.x * blockDim.x) {
        float s[Mm];
#pragma unroll
        for (int m = 0; m < Mm; ++m) s[m] = esb[m * Tt + t];
        const float x0 = imb[t];
        const float x1 = imb[Tt + t];

        acc[0] = fmaf(x0, x0, acc[0]);
        acc[1] = fmaf(x1, x1, acc[1]);
#pragma unroll
        for (int m = 0; m < Mm; ++m) {
            acc[2 + m]     = fmaf(x0, s[m], acc[2 + m]);
            acc[2 + 8 + m] = fmaf(x1, s[m], acc[2 + 8 + m]);
        }
        int p = 18;
#pragma unroll
        for (int m = 0; m < Mm; ++m) {
#pragma unroll
            for (int mp = m; mp < Mm; ++mp, ++p) {
                acc[p] = fmaf(s[m], s[mp], acc[p]);
            }
        }
    }

    // wave-level butterfly reduce, then one atomicAdd per wave leader
    float* wsb = ws + (size_t)b * WS_STRIDE;
#pragma unroll
    for (int i = 0; i < NSTAT; ++i) {
        float v = acc[i];
#pragma unroll
        for (int off = 32; off > 0; off >>= 1) v += __shfl_down(v, off, 64);
        if ((tid & 63) == 0) atomicAdd(&wsb[i], v);
    }
}

// Kernel 2: evaluate all 254 combos per b from the 54 stats, min over combos,
// mean over b. Single block, 256 threads (thread t -> combo bitmask t+1).
__global__ void mixit_finalize_kernel(const float* __restrict__ ws,
                                      float* __restrict__ out) {
    __shared__ float stats[Bb][NSTAT];
    __shared__ float red[4];
    const int tid = threadIdx.x;

    for (int i = tid; i < Bb * NSTAT; i += blockDim.x) {
        stats[i / NSTAT][i % NSTAT] = ws[(size_t)(i / NSTAT) * WS_STRIDE + (i % NSTAT)];
    }
    __syncthreads();

    const int c = tid + 1;             // bitmask; bit m set -> source m in group 1
    const bool valid = (tid < 254);    // c in [1, 254]

    float total = 0.0f;                // meaningful on tid 0 only

    for (int b = 0; b < Bb; ++b) {
        float v = INFINITY;
        if (valid) {
            const float* st = stats[b];
            const float E0 = st[0];
            const float E1 = st[1];
            float ne0 = E0;
            float ne1 = E1;
#pragma unroll
            for (int m = 0; m < Mm; ++m) {
                if ((c >> m) & 1) ne1 -= 2.0f * st[2 + 8 + m];
                else              ne0 -= 2.0f * st[2 + m];
            }
            int p = 18;
#pragma unroll
            for (int m = 0; m < Mm; ++m) {
#pragma unroll
                for (int mp = m; mp < Mm; ++mp, ++p) {
                    const float g = st[p];
                    const float w = (m == mp) ? 1.0f : 2.0f;
                    const int bm  = (c >> m) & 1;
                    const int bmp = (c >> mp) & 1;
                    if (bm & bmp)              ne1 += w * g;
                    else if (!(bm | bmp))      ne0 += w * g;
                }
            }
            // snr_loss_j = -10*log10(E / (ne + TAU*E)) = 10*log10((ne + TAU*E)/E)
            const float snr0 = 10.0f * log10f((ne0 + TAU * E0) / E0);
            const float snr1 = 10.0f * log10f((ne1 + TAU * E1) / E1);
            v = snr0 + snr1;
        }
        // min over 256 threads
#pragma unroll
        for (int off = 32; off > 0; off >>= 1) v = fminf(v, __shfl_down(v, off, 64));
        if ((tid & 63) == 0) red[tid >> 6] = v;
        __syncthreads();
        if (tid == 0) {
            total += fminf(fminf(red[0], red[1]), fminf(red[2], red[3]));
        }
        __syncthreads();
    }

    if (tid == 0) out[0] = total / (float)Bb;
}

extern "C" void kernel_launch(void* const* d_in, const int* in_sizes, int n_in,
                              void* d_out, int out_size, void* d_ws, size_t ws_size,
                              hipStream_t stream) {
    const float* es = (const float*)d_in[0];   // [8, 8, 32000] f32
    const float* im = (const float*)d_in[1];   // [8, 2, 32000] f32
    float* out = (float*)d_out;                // scalar f32
    float* ws  = (float*)d_ws;

    // zero the accumulator region every call (ws is poisoned once, never re-poisoned)
    hipMemsetAsync(ws, 0, (size_t)Bb * WS_STRIDE * sizeof(float), stream);

    dim3 grid(32, Bb);
    mixit_reduce_kernel<<<grid, 256, 0, stream>>>(es, im, ws);
    mixit_finalize_kernel<<<1, 256, 0, stream>>>(ws, out);
}

// Round 2
// 28.074 us; speedup vs baseline: 2.6610x; 2.6610x over previous
//
#include <hip/hip_runtime.h>
#include <math.h>

#define TAU 1e-6f

constexpr int Mm = 8;       // sources
constexpr int Bb = 8;       // batch
constexpr int Tt = 32000;   // time
constexpr int NCOL = Tt / 4;        // 8000 float4 columns per stream
constexpr int BLKS_PER_B = 16;      // kernel-1 blocks per batch element
constexpr int NSTAT = 54;           // 2 E + 16 C + 36 Gram(upper)
constexpr int WS_STRIDE = 64;       // padded per-partial stride in floats

// Stat layout (index): 0..1 E[j]; 2+j*8+m C[j][m]; 18 + i*8 - i(i-1)/2 + (j-i) G[i<=j]
#define STAT_LIST(X) \
  X(e0,0) X(e1,1) \
  X(c00,2) X(c01,3) X(c02,4) X(c03,5) X(c04,6) X(c05,7) X(c06,8) X(c07,9) \
  X(c10,10) X(c11,11) X(c12,12) X(c13,13) X(c14,14) X(c15,15) X(c16,16) X(c17,17) \
  X(g00,18) X(g01,19) X(g02,20) X(g03,21) X(g04,22) X(g05,23) X(g06,24) X(g07,25) \
  X(g11,26) X(g12,27) X(g13,28) X(g14,29) X(g15,30) X(g16,31) X(g17,32) \
  X(g22,33) X(g23,34) X(g24,35) X(g25,36) X(g26,37) X(g27,38) \
  X(g33,39) X(g34,40) X(g35,41) X(g36,42) X(g37,43) \
  X(g44,44) X(g45,45) X(g46,46) X(g47,47) \
  X(g55,48) X(g56,49) X(g57,50) \
  X(g66,51) X(g67,52) \
  X(g77,53)

#define DECL_STAT(v,i) float v = 0.0f;

// one float4 component's worth of FMA updates (all named scalars -> registers)
#define COMP_UPDATE(F) do { \
  const float x0 = x0v.F, x1 = x1v.F; \
  const float t0 = s0v.F, t1 = s1v.F, t2 = s2v.F, t3 = s3v.F; \
  const float t4 = s4v.F, t5 = s5v.F, t6 = s6v.F, t7 = s7v.F; \
  e0 = fmaf(x0, x0, e0);  e1 = fmaf(x1, x1, e1); \
  c00 = fmaf(x0, t0, c00); c01 = fmaf(x0, t1, c01); c02 = fmaf(x0, t2, c02); c03 = fmaf(x0, t3, c03); \
  c04 = fmaf(x0, t4, c04); c05 = fmaf(x0, t5, c05); c06 = fmaf(x0, t6, c06); c07 = fmaf(x0, t7, c07); \
  c10 = fmaf(x1, t0, c10); c11 = fmaf(x1, t1, c11); c12 = fmaf(x1, t2, c12); c13 = fmaf(x1, t3, c13); \
  c14 = fmaf(x1, t4, c14); c15 = fmaf(x1, t5, c15); c16 = fmaf(x1, t6, c16); c17 = fmaf(x1, t7, c17); \
  g00 = fmaf(t0, t0, g00); g01 = fmaf(t0, t1, g01); g02 = fmaf(t0, t2, g02); g03 = fmaf(t0, t3, g03); \
  g04 = fmaf(t0, t4, g04); g05 = fmaf(t0, t5, g05); g06 = fmaf(t0, t6, g06); g07 = fmaf(t0, t7, g07); \
  g11 = fmaf(t1, t1, g11); g12 = fmaf(t1, t2, g12); g13 = fmaf(t1, t3, g13); g14 = fmaf(t1, t4, g14); \
  g15 = fmaf(t1, t5, g15); g16 = fmaf(t1, t6, g16); g17 = fmaf(t1, t7, g17); \
  g22 = fmaf(t2, t2, g22); g23 = fmaf(t2, t3, g23); g24 = fmaf(t2, t4, g24); g25 = fmaf(t2, t5, g25); \
  g26 = fmaf(t2, t6, g26); g27 = fmaf(t2, t7, g27); \
  g33 = fmaf(t3, t3, g33); g34 = fmaf(t3, t4, g34); g35 = fmaf(t3, t5, g35); g36 = fmaf(t3, t6, g36); \
  g37 = fmaf(t3, t7, g37); \
  g44 = fmaf(t4, t4, g44); g45 = fmaf(t4, t5, g45); g46 = fmaf(t4, t6, g46); g47 = fmaf(t4, t7, g47); \
  g55 = fmaf(t5, t5, g55); g56 = fmaf(t5, t6, g56); g57 = fmaf(t5, t7, g57); \
  g66 = fmaf(t6, t6, g66); g67 = fmaf(t6, t7, g67); \
  g77 = fmaf(t7, t7, g77); \
} while (0)

#define REDUCE_STORE(v,i) { \
  float r_ = v; \
  r_ += __shfl_down(r_, 32, 64); r_ += __shfl_down(r_, 16, 64); \
  r_ += __shfl_down(r_, 8, 64);  r_ += __shfl_down(r_, 4, 64); \
  r_ += __shfl_down(r_, 2, 64);  r_ += __shfl_down(r_, 1, 64); \
  if (lane == 0) sh[wv][i] = r_; \
}

// Kernel 1: per-(b, block) partial Gram stats over a slice of T.
__global__ void __launch_bounds__(256) mixit_reduce_kernel(
    const float* __restrict__ es,
    const float* __restrict__ im,
    float* __restrict__ ws) {
    const int b   = blockIdx.y;
    const int tid = threadIdx.x;

    STAT_LIST(DECL_STAT)

    const float4* esb4 = (const float4*)(es + (size_t)b * Mm * Tt);
    const float4* imb4 = (const float4*)(im + (size_t)b * 2 * Tt);

    for (int col = blockIdx.x * blockDim.x + tid; col < NCOL;
         col += BLKS_PER_B * blockDim.x) {
        const float4 x0v = imb4[col];
        const float4 x1v = imb4[NCOL + col];
        const float4 s0v = esb4[0 * NCOL + col];
        const float4 s1v = esb4[1 * NCOL + col];
        const float4 s2v = esb4[2 * NCOL + col];
        const float4 s3v = esb4[3 * NCOL + col];
        const float4 s4v = esb4[4 * NCOL + col];
        const float4 s5v = esb4[5 * NCOL + col];
        const float4 s6v = esb4[6 * NCOL + col];
        const float4 s7v = esb4[7 * NCOL + col];
        COMP_UPDATE(x);
        COMP_UPDATE(y);
        COMP_UPDATE(z);
        COMP_UPDATE(w);
    }

    __shared__ float sh[4][NSTAT];
    const int lane = tid & 63;
    const int wv   = tid >> 6;

    STAT_LIST(REDUCE_STORE)

    __syncthreads();
    if (tid < NSTAT) {
        const float p = sh[0][tid] + sh[1][tid] + sh[2][tid] + sh[3][tid];
        ws[((size_t)b * BLKS_PER_B + blockIdx.x) * WS_STRIDE + tid] = p;
    }
}

// Kernel 2: sum block-partials, evaluate 254 combos per b, min, mean.
// 512 threads: wave w owns batch b=w; lane covers combos lane, lane+64, +128, +192.
__global__ void __launch_bounds__(512) mixit_finalize_kernel(
    const float* __restrict__ ws,
    float* __restrict__ out) {
    __shared__ float stats[Bb][NSTAT];
    __shared__ float minb[Bb];
    const int tid = threadIdx.x;

    for (int i = tid; i < Bb * NSTAT; i += 512) {
        const int b = i / NSTAT, s = i % NSTAT;
        const float* base = ws + (size_t)b * BLKS_PER_B * WS_STRIDE + s;
        float acc = 0.0f;
#pragma unroll
        for (int k = 0; k < BLKS_PER_B; ++k) acc += base[k * WS_STRIDE];
        stats[b][s] = acc;
    }
    __syncthreads();

    const int wv   = tid >> 6;
    const int lane = tid & 63;
    const float* st = stats[wv];
    const float E0 = st[0];
    const float E1 = st[1];

    float vmin = INFINITY;
#pragma unroll
    for (int ci = 0; ci < 4; ++ci) {
        const int cm1 = lane + 64 * ci;     // combo - 1, in [0, 255]
        if (cm1 < 254) {
            const int c = cm1 + 1;          // bitmask; bit m set -> source m in group 1
            float ne0 = E0;
            float ne1 = E1;
#pragma unroll
            for (int m = 0; m < Mm; ++m) {
                if ((c >> m) & 1) ne1 -= 2.0f * st[10 + m];
                else              ne0 -= 2.0f * st[2 + m];
            }
            int p = 18;
#pragma unroll
            for (int m = 0; m < Mm; ++m) {
#pragma unroll
                for (int mp = m; mp < Mm; ++mp, ++p) {
                    const float g = st[p];
                    const float w = (m == mp) ? 1.0f : 2.0f;
                    const int bm  = (c >> m) & 1;
                    const int bmp = (c >> mp) & 1;
                    if (bm & bmp)         ne1 += w * g;
                    else if (!(bm | bmp)) ne0 += w * g;
                }
            }
            // snr_loss_j = 10*log10((ne + TAU*E)/E); sum over j=0,1
            const float snr = 10.0f * log10f((ne0 + TAU * E0) / E0)
                            + 10.0f * log10f((ne1 + TAU * E1) / E1);
            vmin = fminf(vmin, snr);
        }
    }
#pragma unroll
    for (int off = 32; off > 0; off >>= 1) vmin = fminf(vmin, __shfl_down(vmin, off, 64));
    if (lane == 0) minb[wv] = vmin;
    __syncthreads();

    if (tid == 0) {
        float tot = 0.0f;
#pragma unroll
        for (int i = 0; i < Bb; ++i) tot += minb[i];
        out[0] = tot / (float)Bb;
    }
}

extern "C" void kernel_launch(void* const* d_in, const int* in_sizes, int n_in,
                              void* d_out, int out_size, void* d_ws, size_t ws_size,
                              hipStream_t stream) {
    const float* es = (const float*)d_in[0];   // [8, 8, 32000] f32
    const float* im = (const float*)d_in[1];   // [8, 2, 32000] f32
    float* out = (float*)d_out;                // scalar f32
    float* ws  = (float*)d_ws;                 // [8][16][64] f32 partials

    dim3 grid(BLKS_PER_B, Bb);
    mixit_reduce_kernel<<<grid, 256, 0, stream>>>(es, im, ws);
    mixit_finalize_kernel<<<1, 512, 0, stream>>>(ws, out);
}